// Round 2
// baseline (303.242 us; speedup 1.0000x reference)
//
#include <hip/hip_runtime.h>
#include <stdint.h>

// DCT2D: y = Dh @ x @ Dw^T per (b,c); B=32,H=W=512,C=3, fp32 in/out.
// Round 2: W-DCT first (x staging coalesced), bf16 intermediate Y1[b,c,l,h]
// (h-contiguous), then H-DCT with both operands k-contiguous. BK=64,
// register-prefetch pipelining, swizzled LDS layouts.

typedef __bf16 bf16_t;
typedef bf16_t bf16x8 __attribute__((ext_vector_type(8)));
typedef bf16_t bf16x4 __attribute__((ext_vector_type(4)));
typedef float  f32x4  __attribute__((ext_vector_type(4)));

__device__ __forceinline__ uint32_t f2bf(float f) {
    union { float f; uint32_t u; } v; v.f = f;
    uint32_t r = v.u + 0x7fffu + ((v.u >> 16) & 1u);   // RNE
    return r >> 16;
}

__device__ __forceinline__ f32x4 mfma16(bf16x8 a, bf16x8 b, f32x4 c) {
    return __builtin_amdgcn_mfma_f32_16x16x32_bf16(a, b, c, 0, 0, 0);
}

__device__ __forceinline__ void load_lds16(const void* g, void* l) {
    __builtin_amdgcn_global_load_lds(
        (const __attribute__((address_space(1))) uint32_t*)g,
        (__attribute__((address_space(3))) uint32_t*)l, 16, 0, 0);
}

// ---------------- D matrix generation (bf16, row-major D[k][h]) -------------
__global__ __launch_bounds__(256) void gen_dct(uint16_t* __restrict__ Dbf) {
    int idx = blockIdx.x * 256 + threadIdx.x;      // 512*512 elems
    int k = idx >> 9, h = idx & 511;
    int phase = ((2 * h + 1) * k) & 2047;          // exact mod-2048 reduction
    float ang = (float)phase * 3.0679615757712823e-3f;   // pi/1024
    float s = (k == 0) ? 0.04419417382415922f : 0.0625f; // sqrt(1/512), sqrt(2/512)
    Dbf[idx] = (uint16_t)f2bf(__cosf(ang) * s);
}

// ---------------- Pass W: Y1[b,c,l,h] = sum_w x[b,h,w,c] * D[l,w] -----------
// GEMM per b: C[m=(c,h) 96][n=l 128], K=w 512, BK=64, 8 iters.
// A = x tile: coalesced float4 loads -> regs -> bf16 pack -> LDS (rotated).
// B = D tile via global_load_lds (XOR chunk placement).
__global__ __launch_bounds__(256, 4) void pass_w(const float* __restrict__ x,
                                                 const uint16_t* __restrict__ Dbf,
                                                 uint16_t* __restrict__ Y1) {
    __shared__ __align__(16) uint16_t Ax[96 * 64];    // 12288 B, row=(c*32+hl), col=w (rotated)
    __shared__ __align__(16) uint16_t Bd[128 * 64];   // 16384 B, chunk-XOR layout
    const int t = threadIdx.x, lane = t & 63, wv = t >> 6;
    const int quad = lane >> 4, l15 = lane & 15;
    const int lt = blockIdx.x;   // l-tile 0..3
    const int ht = blockIdx.y;   // h-tile 0..15
    const int b  = blockIdx.z;

    // x staging: thread -> (hl = t>>3, wq = t&7); 24 consecutive floats.
    const int hl = t >> 3, wq = t & 7;
    const float* xrow = x + (size_t)b * 786432 + (size_t)(ht * 32 + hl) * 1536 + wq * 24;

    // D staging chunk sources (XOR placement: LDS pos p holds (row=p>>3, j=(p&7)^(row&7)))
    const uint16_t* srcD[4];
#pragma unroll
    for (int i = 0; i < 4; ++i) {
        int p = i * 256 + t, row = p >> 3, jj = (p & 7) ^ (row & 7);
        srcD[i] = Dbf + (size_t)(lt * 128 + row) * 512 + jj * 8;
    }

    float4 xr[6];
#pragma unroll
    for (int i = 0; i < 6; ++i) xr[i] = *(const float4*)(xrow + i * 4);

    f32x4 acc[6][2] = {};

    for (int kt = 0; kt < 8; ++kt) {
        __syncthreads();
#pragma unroll
        for (int i = 0; i < 4; ++i)
            load_lds16(srcD[i] + kt * 64, Bd + (i * 256 + t) * 8);
        // pack held x regs -> Ax (c-deinterleave, 8 w per write)
        {
            const float* xf = (const float*)xr;
            const int wsw = ((wq + (hl & 7)) & 7) * 8;   // row-rotation swizzle
#pragma unroll
            for (int c = 0; c < 3; ++c) {
                bf16x8 hv;
#pragma unroll
                for (int u = 0; u < 8; ++u) hv[u] = (bf16_t)xf[c + 3 * u];
                *(bf16x8*)&Ax[(c * 32 + hl) * 64 + wsw] = hv;
            }
        }
        __syncthreads();
        if (kt < 7) {   // prefetch next x tile: latency overlaps compute below
#pragma unroll
            for (int i = 0; i < 6; ++i)
                xr[i] = *(const float4*)(xrow + (kt + 1) * 192 + i * 4);
        }
#pragma unroll
        for (int ks = 0; ks < 2; ++ks) {
            bf16x8 aq[6], bq[2];
#pragma unroll
            for (int tt = 0; tt < 6; ++tt) {
                int m = tt * 16 + l15;
                int ws = ((ks * 4 + quad + (m & 7)) & 7) * 8;
                aq[tt] = *(const bf16x8*)&Ax[m * 64 + ws];
            }
#pragma unroll
            for (int p = 0; p < 2; ++p) {
                int n = wv * 32 + p * 16 + l15;
                int pos = n * 8 + ((ks * 4 + quad) ^ (n & 7));
                bq[p] = *(const bf16x8*)&Bd[pos * 8];
            }
#pragma unroll
            for (int tt = 0; tt < 6; ++tt)
#pragma unroll
                for (int p = 0; p < 2; ++p)
                    acc[tt][p] = mfma16(aq[tt], bq[p], acc[tt][p]);
        }
    }

    // Epilogue: m = tt*16 + quad*4 + r -> (c = tt>>1, h-in-tile); n = l.
    // 4 consecutive h -> 8 B packed store, h-contiguous target.
#pragma unroll
    for (int tt = 0; tt < 6; ++tt) {
        const int c = tt >> 1;
        const int hb = (tt & 1) * 16 + quad * 4;
#pragma unroll
        for (int p = 0; p < 2; ++p) {
            int n = wv * 32 + p * 16 + l15;
            bf16x4 pk;
#pragma unroll
            for (int r = 0; r < 4; ++r) pk[r] = (bf16_t)acc[tt][p][r];
            *(bf16x4*)&Y1[(size_t)b * 786432 + (size_t)c * 262144 +
                          (size_t)(lt * 128 + n) * 512 + ht * 32 + hb] = pk;
        }
    }
}

// ---------------- Pass H: out[b,k,l,c] = sum_h D[k,h] * Y1[b,c,l,h] ---------
// GEMM per b: C[m=k 128][n=(c,l) 96], K=h 512, BK=64, 8 iters.
// A = D via global_load_lds; B = Y1 via reg-prefetch -> LDS (both XOR layout).
__global__ __launch_bounds__(256, 4) void pass_h(const uint16_t* __restrict__ Y1,
                                                 const uint16_t* __restrict__ Dbf,
                                                 float* __restrict__ out) {
    __shared__ __align__(16) char smem[28672];
    uint16_t* Ad = (uint16_t*)smem;             // 128*64 bf16 = 16384 B
    uint16_t* By = (uint16_t*)(smem + 16384);   // 96*64 bf16 = 12288 B
    float*    El = (float*)smem;                // epilogue: 64 x 100 fp32 (25600 B)
    const int t = threadIdx.x, lane = t & 63, wv = t >> 6;
    const int quad = lane >> 4, l15 = lane & 15;
    const int ktile = blockIdx.x;   // k-tile 0..3
    const int lt = blockIdx.y;      // l-tile 0..15
    const int b  = blockIdx.z;
    const int l0 = lt * 32;

    const uint16_t* srcA[4];
#pragma unroll
    for (int i = 0; i < 4; ++i) {
        int p = i * 256 + t, row = p >> 3, jj = (p & 7) ^ (row & 7);
        srcA[i] = Dbf + (size_t)(ktile * 128 + row) * 512 + jj * 8;
    }
    const uint16_t* srcB[3];
#pragma unroll
    for (int i = 0; i < 3; ++i) {
        int p = i * 256 + t, row = p >> 3, jj = (p & 7) ^ (row & 7);
        srcB[i] = Y1 + (size_t)b * 786432 + (size_t)(row >> 5) * 262144 +
                  (size_t)(l0 + (row & 31)) * 512 + jj * 8;
    }

    uint4 yr[3];
#pragma unroll
    for (int i = 0; i < 3; ++i) yr[i] = *(const uint4*)srcB[i];

    f32x4 acc[6][2] = {};

    for (int kt = 0; kt < 8; ++kt) {
        __syncthreads();
#pragma unroll
        for (int i = 0; i < 4; ++i)
            load_lds16(srcA[i] + kt * 64, Ad + (i * 256 + t) * 8);
#pragma unroll
        for (int i = 0; i < 3; ++i)
            *(uint4*)&By[(i * 256 + t) * 8] = yr[i];
        __syncthreads();
        if (kt < 7) {   // prefetch next Y1 tile (HBM latency overlaps compute)
#pragma unroll
            for (int i = 0; i < 3; ++i)
                yr[i] = *(const uint4*)(srcB[i] + (kt + 1) * 64);
        }
#pragma unroll
        for (int ks = 0; ks < 2; ++ks) {
            bf16x8 aq[2], bq[6];
#pragma unroll
            for (int p = 0; p < 2; ++p) {
                int m = wv * 32 + p * 16 + l15;
                int pos = m * 8 + ((ks * 4 + quad) ^ (m & 7));
                aq[p] = *(const bf16x8*)&Ad[pos * 8];
            }
#pragma unroll
            for (int tt = 0; tt < 6; ++tt) {
                int n = tt * 16 + l15;
                int pos = n * 8 + ((ks * 4 + quad) ^ (n & 7));
                bq[tt] = *(const bf16x8*)&By[pos * 8];
            }
#pragma unroll
            for (int tt = 0; tt < 6; ++tt)
#pragma unroll
                for (int p = 0; p < 2; ++p)
                    acc[tt][p] = mfma16(aq[p], bq[tt], acc[tt][p]);
        }
    }

    // Epilogue: two k-halves through El[64][100]; contiguous 384 B runs per k.
    const int sub = t & 3, krow = t >> 2;
#pragma unroll
    for (int ph = 0; ph < 2; ++ph) {
        __syncthreads();
        if ((wv >> 1) == ph) {
#pragma unroll
            for (int p = 0; p < 2; ++p) {
                int idx2 = wv * 2 + p;               // m = idx2*16 + quad*4 + r
                int kb = (idx2 & 3) * 16 + quad * 4; // m & 63
#pragma unroll
                for (int tt = 0; tt < 6; ++tt) {
                    int n = tt * 16 + l15;
                    int col = (n & 31) * 3 + (n >> 5);   // (l-local)*3 + c
#pragma unroll
                    for (int r = 0; r < 4; ++r)
                        El[(kb + r) * 100 + col] = acc[tt][p][r];
                }
            }
        }
        __syncthreads();
        float* dst = out + (size_t)b * 786432 +
                     (size_t)(ktile * 128 + ph * 64 + krow) * 1536 + lt * 96 + sub * 24;
        const float* srcE = El + krow * 100 + sub * 24;
#pragma unroll
        for (int i = 0; i < 6; ++i)
            *(float4*)(dst + i * 4) = *(const float4*)(srcE + i * 4);
    }
}

// ---------------------------------------------------------------------------
extern "C" void kernel_launch(void* const* d_in, const int* in_sizes, int n_in,
                              void* d_out, int out_size, void* d_ws, size_t ws_size,
                              hipStream_t stream) {
    (void)in_sizes; (void)n_in; (void)out_size; (void)ws_size;
    const float* x = (const float*)d_in[0];
    float* out = (float*)d_out;
    uint16_t* Dbf = (uint16_t*)d_ws;                 // 512*512 bf16 = 512 KB
    uint16_t* Y1  = (uint16_t*)d_ws + 512 * 512;     // 32*3*512*512 bf16 = 48 MB

    gen_dct<<<1024, 256, 0, stream>>>(Dbf);
    dim3 g1(4, 16, 32);
    pass_w<<<g1, 256, 0, stream>>>(x, Dbf, Y1);
    dim3 g2(4, 16, 32);
    pass_h<<<g2, 256, 0, stream>>>(Y1, Dbf, out);
}